// Round 2
// baseline (1379.644 us; speedup 1.0000x reference)
//
#include <hip/hip_runtime.h>
#include <hip/hip_fp16.h>
#include <cstddef>
#include <cstdint>

typedef _Float16 f16;
typedef _Float16 f16x8 __attribute__((ext_vector_type(8)));
typedef _Float16 f16x4 __attribute__((ext_vector_type(4)));
typedef float    f32x4 __attribute__((ext_vector_type(4)));

#define BK 32
#define LDT 40   // padded LDS row stride in fp16 elems (80 B; 16B-aligned frags)

// Stage a [R x 32] tile (rows at stride ld, f32 or f16 source) into LDS as fp16.
// R=128: 2 threads/row x 16 elems; R=64: 4 threads/row x 8 elems.
template<int R, typename T>
__device__ __forceinline__ void stage_tile(f16 (*dst)[LDT], const T* __restrict__ src,
                                           size_t ld, int tid)
{
  constexpr int EPT = R / 8;       // fp16 elems per thread (16 or 8)
  constexpr int TPR = 32 / EPT;    // threads per row (2 or 4)
  const int sr = tid / TPR;
  const int sh = (tid % TPR) * EPT;
  const T* s = src + (size_t)sr * ld + sh;
  f16 tmp[EPT];
  if constexpr (sizeof(T) == 4) {
#pragma unroll
    for (int v = 0; v < EPT / 4; v++) {
      const float4 x = ((const float4*)s)[v];
      tmp[v * 4 + 0] = (f16)x.x; tmp[v * 4 + 1] = (f16)x.y;
      tmp[v * 4 + 2] = (f16)x.z; tmp[v * 4 + 3] = (f16)x.w;
    }
  } else {
#pragma unroll
    for (int v = 0; v < EPT / 8; v++)
      *(f16x8*)&tmp[v * 8] = ((const f16x8*)s)[v];
  }
#pragma unroll
  for (int v = 0; v < EPT / 8; v++)
    *(f16x8*)&dst[sr][sh + v * 8] = *(f16x8*)&tmp[v * 8];
}

// ---------------------------------------------------------------------------
// TN GEMM: C[M][N] = A[M][K] @ B[N][K]^T  (+bias[n]) (+relu)
// A row-major (lda), B row-major N x K (ldb), C row-major (ldc).
// TA/TB in {float, f16} (f32 converted to fp16 during staging). TC in {float, f16}.
// 256 threads = 4 waves (2x2); wave tile (BMt/2 x BNt/2); mfma_f32_16x16x32_f16.
// ---------------------------------------------------------------------------
template<int BMt, int BNt, typename TA, typename TB, bool BIAS, bool RELU, typename TC>
__global__ __launch_bounds__(256, 2)
void gemm_tn(const TA* __restrict__ A, int lda,
             const TB* __restrict__ B, int ldb,
             TC* __restrict__ C, int ldc,
             const float* __restrict__ bias, int K)
{
  constexpr int MF = BMt / 32;   // frags per wave in M
  constexpr int NF = BNt / 32;   // frags per wave in N
  __shared__ f16 As[BMt][LDT];
  __shared__ f16 Bs[BNt][LDT];
  const int tid  = threadIdx.x;
  const int lane = tid & 63;
  const int wid  = tid >> 6;
  const int wr   = wid >> 1;
  const int wc   = wid & 1;
  const int m0   = blockIdx.x * BMt;
  const int n0   = blockIdx.y * BNt;

  f32x4 acc[MF][NF] = {};

  for (int k0 = 0; k0 < K; k0 += BK) {
    stage_tile<BMt>(As, A + (size_t)m0 * lda + k0, lda, tid);
    stage_tile<BNt>(Bs, B + (size_t)n0 * ldb + k0, ldb, tid);
    __syncthreads();

    const int fr = lane & 15;
    const int kg = (lane >> 4) << 3;
    f16x8 af[MF], bf[NF];
#pragma unroll
    for (int i = 0; i < MF; i++)
      af[i] = *(const f16x8*)&As[wr * (BMt / 2) + i * 16 + fr][kg];
#pragma unroll
    for (int j = 0; j < NF; j++)
      bf[j] = *(const f16x8*)&Bs[wc * (BNt / 2) + j * 16 + fr][kg];
#pragma unroll
    for (int i = 0; i < MF; i++)
#pragma unroll
      for (int j = 0; j < NF; j++)
        acc[i][j] = __builtin_amdgcn_mfma_f32_16x16x32_f16(af[i], bf[j], acc[i][j], 0, 0, 0);
    __syncthreads();
  }

  // epilogue: D layout col = lane&15, row = (lane>>4)*4 + r (m89-verified)
  const int fr = lane & 15;
  const int rg = (lane >> 4) << 2;
#pragma unroll
  for (int i = 0; i < MF; i++) {
#pragma unroll
    for (int j = 0; j < NF; j++) {
      const int col = n0 + wc * (BNt / 2) + j * 16 + fr;
      float bv = 0.f;
      if constexpr (BIAS) bv = bias[col];
#pragma unroll
      for (int r = 0; r < 4; r++) {
        const int row = m0 + wr * (BMt / 2) + i * 16 + rg + r;
        float v = acc[i][j][r] + bv;
        if constexpr (RELU) v = fmaxf(v, 0.f);
        C[(size_t)row * ldc + col] = (TC)v;
      }
    }
  }
}

// ---------------------------------------------------------------------------
// Transpose f32 -> fp16: in[R][Cn] f32 -> outT[Cn][R] fp16.
// ---------------------------------------------------------------------------
__global__ __launch_bounds__(256)
void transpose_f32_f16(const float* __restrict__ in, int R, int Cn,
                       f16* __restrict__ outT)
{
  __shared__ float t[32][33];
  const int r0 = blockIdx.x * 32;
  const int c0 = blockIdx.y * 32;
  const int c  = threadIdx.x & 31;
  const int rq = threadIdx.x >> 5;
#pragma unroll
  for (int i = 0; i < 4; i++) {
    const int r = rq + i * 8;
    t[r][c] = in[(size_t)(r0 + r) * Cn + c0 + c];
  }
  __syncthreads();
#pragma unroll
  for (int i = 0; i < 4; i++) {
    const int r = rq + i * 8;
    outT[(size_t)(c0 + r) * R + r0 + c] = (f16)t[c][r];
  }
}

// ---------------------------------------------------------------------------
// Row softmax over 2048 f32 scores; writes normalized P as fp16 packed into
// the first 4KB of the row (in-place, per-row ownership -> race-free).
// ---------------------------------------------------------------------------
__global__ __launch_bounds__(256)
void softmax_rows(float* __restrict__ S)
{
  float* row = S + (size_t)blockIdx.x * 2048;
  const int t = threadIdx.x;
  const float4 v0 = ((const float4*)row)[t];
  const float4 v1 = ((const float4*)row)[t + 256];

  float m = fmaxf(fmaxf(fmaxf(v0.x, v0.y), fmaxf(v0.z, v0.w)),
                  fmaxf(fmaxf(v1.x, v1.y), fmaxf(v1.z, v1.w)));
#pragma unroll
  for (int off = 32; off > 0; off >>= 1) m = fmaxf(m, __shfl_xor(m, off));
  __shared__ float red[8];
  if ((t & 63) == 0) red[t >> 6] = m;
  __syncthreads();
  m = fmaxf(fmaxf(red[0], red[1]), fmaxf(red[2], red[3]));

  float e0 = __expf(v0.x - m), e1 = __expf(v0.y - m), e2 = __expf(v0.z - m), e3 = __expf(v0.w - m);
  float e4 = __expf(v1.x - m), e5 = __expf(v1.y - m), e6 = __expf(v1.z - m), e7 = __expf(v1.w - m);
  float s = ((e0 + e1) + (e2 + e3)) + ((e4 + e5) + (e6 + e7));
#pragma unroll
  for (int off = 32; off > 0; off >>= 1) s += __shfl_xor(s, off);
  if ((t & 63) == 0) red[4 + (t >> 6)] = s;
  __syncthreads();
  const float inv = 1.f / (red[4] + red[5] + red[6] + red[7]);

  f16x4 o0, o1;
  o0[0] = (f16)(e0 * inv); o0[1] = (f16)(e1 * inv); o0[2] = (f16)(e2 * inv); o0[3] = (f16)(e3 * inv);
  o1[0] = (f16)(e4 * inv); o1[1] = (f16)(e5 * inv); o1[2] = (f16)(e6 * inv); o1[3] = (f16)(e7 * inv);
  f16x4* orow = (f16x4*)row;
  orow[t]       = o0;
  orow[t + 256] = o1;
}

// ---------------------------------------------------------------------------
extern "C" void kernel_launch(void* const* d_in, const int* in_sizes, int n_in,
                              void* d_out, int out_size, void* d_ws, size_t ws_size,
                              hipStream_t stream)
{
  const float* x1   = (const float*)d_in[0];
  const float* x2   = (const float*)d_in[1];
  const float* U    = (const float*)d_in[2];
  const float* bias = (const float*)d_in[3];
  const float* fcw  = (const float*)d_in[4];
  const float* fcb  = (const float*)d_in[5];
  float* out = (float*)d_out;

  const int S = 2048, D = 1024, E = 512, B = 8;
  const int SC = 1024;                 // s-chunk (ws budget: 18 MB total)
  const size_t MB = 1ull << 20;

  // ws layout: UT 2MB | X1T 4MB | Y(/O overlay) 4MB | Sb 8MB  = 18MB
  char* w = (char*)d_ws;
  f16*   UT  = (f16*)(w);
  f16*   X1T = (f16*)(w + 2 * MB);
  f16*   Y   = (f16*)(w + 6 * MB);
  float* Sb  = (float*)(w + 10 * MB);

  // U [d][d] -> UT [d][d]^T fp16 (once)
  transpose_f32_f16<<<dim3(32, 32), 256, 0, stream>>>(U, D, D, UT);

  for (int b = 0; b < B; b++) {
    const float* x1b = x1 + (size_t)b * S * D;
    const float* x2b = x2 + (size_t)b * S * D;

    // x1_b [S][D] -> X1T [D][S] fp16
    transpose_f32_f16<<<dim3(64, 32), 256, 0, stream>>>(x1b, S, D, X1T);

    // K1: Y = x2_b @ U + bias   (A=x2 f32 direct, B=UT fp16)   grid 256
    gemm_tn<64, 128, float, f16, true, false, f16><<<dim3(32, 8), 256, 0, stream>>>(
        x2b, D, UT, D, Y, D, bias, D);

    for (int s0 = 0; s0 < S; s0 += SC) {
      // K2: Sb = Y'[s0:s0+SC] @ x1^T   (B=x1 f32 direct, K=d)  grid 256
      gemm_tn<64, 128, f16, float, false, false, float><<<dim3(SC / 64, S / 128), 256, 0, stream>>>(
          Y + (size_t)s0 * D, D, x1b, D, Sb, S, nullptr, D);
      // K3: softmax rows -> P fp16 packed in-place
      softmax_rows<<<dim3(SC), 256, 0, stream>>>(Sb);
      // K4: O = P @ x1  (A=P fp16 lda=2S, B=X1T, K=t) ; O overlays Y[s0:]  grid 256
      gemm_tn<64, 64, f16, f16, false, false, f16><<<dim3(SC / 64, D / 64), 256, 0, stream>>>(
          (const f16*)Sb, 2 * S, X1T, S, Y + (size_t)s0 * D, D, nullptr, S);
    }

    // K5: out_b = relu(O @ fc_w^T + fc_b)  (A=O fp16 full S, B=fcw f32)  grid 256
    gemm_tn<64, 64, f16, float, true, true, float><<<dim3(S / 64, E / 64), 256, 0, stream>>>(
        Y, D, fcw, D, out + (size_t)b * S * E, E, fcb, D);
  }
}

// Round 3
// 1246.452 us; speedup vs baseline: 1.1069x; 1.1069x over previous
//
#include <hip/hip_runtime.h>
#include <hip/hip_fp16.h>
#include <cstddef>
#include <cstdint>

typedef _Float16 f16;
typedef _Float16 f16x8 __attribute__((ext_vector_type(8)));
typedef _Float16 f16x4 __attribute__((ext_vector_type(4)));
typedef float    f32x4 __attribute__((ext_vector_type(4)));

#define BK 64   // K-tile depth (fp16 elems); 2 MFMA k-steps per tile

// async 16B global->LDS (linear LDS dest = wave-uniform base + lane*16)
__device__ __forceinline__ void gload16(const void* g, void* lds) {
  __builtin_amdgcn_global_load_lds(
      (const __attribute__((address_space(1))) unsigned int*)g,
      (__attribute__((address_space(3))) unsigned int*)lds, 16, 0, 0);
}

// Stage an [R x 64] fp16 tile via global_load_lds. LDS layout: row r holds
// global 8-elem slot s at LDS slot s^(r&7) (bank-conflict swizzle, rule-21
// both-sides: source address pre-swizzled here, reader XORs the same way).
template<int R>
__device__ __forceinline__ void stage_f16(f16 (*buf)[BK], const f16* __restrict__ src,
                                          int ld, int w, int lane) {
#pragma unroll
  for (int i = 0; i < R / 32; i++) {
    const int grp  = w * (R / 32) + i;          // wave-uniform
    const int r    = grp * 8 + (lane >> 3);
    const int slot = (lane & 7) ^ (r & 7);
    gload16(src + (size_t)r * ld + slot * 8, &buf[grp * 8][0]);
  }
}

// Reg-staging for f32 sources (issue-early / write-late, T14 split):
// load() before the MFMA phase, write() after it.
template<int R>
struct RegStage {
  static constexpr int NV = (R == 128) ? 8 : 4;   // float4 loads per thread
  float4 v[NV];
  __device__ __forceinline__ void load(const float* __restrict__ src, int ld, int tid) {
    const int r = (R == 128) ? (tid >> 1) : (tid >> 2);
    const int h = (R == 128) ? (tid & 1) * 32 : (tid & 3) * 16;
    const float* p = src + (size_t)r * ld + h;
#pragma unroll
    for (int j = 0; j < NV; j++) v[j] = ((const float4*)p)[j];
  }
  __device__ __forceinline__ void write(f16 (*buf)[BK], int tid) {
    const int r = (R == 128) ? (tid >> 1) : (tid >> 2);
    const int h = (R == 128) ? (tid & 1) * 32 : (tid & 3) * 16;
#pragma unroll
    for (int g = 0; g < NV / 2; g++) {
      const float4 a = v[g * 2], b = v[g * 2 + 1];
      f16x8 o;
      o[0] = (f16)a.x; o[1] = (f16)a.y; o[2] = (f16)a.z; o[3] = (f16)a.w;
      o[4] = (f16)b.x; o[5] = (f16)b.y; o[6] = (f16)b.z; o[7] = (f16)b.w;
      const int slot = (h / 8 + g) ^ (r & 7);
      *(f16x8*)&buf[r][slot * 8] = o;
    }
  }
};

// ---------------------------------------------------------------------------
// TN GEMM, double-buffered: C[M][N] = A[M][K] @ B[N][K]^T (+bias) (+relu).
// fp16 operands: global_load_lds direct. f32 operands: reg-stage + cvt.
// 256 threads = 4 waves (2x2); per-tile 2 MFMA k-steps (16x16x32 f16).
// ---------------------------------------------------------------------------
template<int BMt, int BNt, typename TA, typename TB, bool BIAS, bool RELU, typename TC>
__global__ void gemm_tn(const TA* __restrict__ A, int lda,
                        const TB* __restrict__ B, int ldb,
                        TC* __restrict__ C, int ldc,
                        const float* __restrict__ bias, int K)
{
  constexpr int MF = BMt / 32;
  constexpr int NF = BNt / 32;
  __shared__ f16 As[2][BMt][BK];
  __shared__ f16 Bs[2][BNt][BK];
  const int tid  = threadIdx.x;
  const int lane = tid & 63;
  const int w    = tid >> 6;
  const int wr   = w >> 1, wc = w & 1;
  const int m0   = blockIdx.x * BMt;
  const int n0   = blockIdx.y * BNt;

  f32x4 acc[MF][NF] = {};
  RegStage<BMt> ra;   // dead (eliminated) when TA == f16
  RegStage<BNt> rb;   // dead when TB == f16

  auto stage_issue = [&](int buf, int k0) {
    if constexpr (sizeof(TA) == 2)
      stage_f16<BMt>(As[buf], (const f16*)A + (size_t)m0 * lda + k0, lda, w, lane);
    else
      ra.load((const float*)A + (size_t)m0 * lda + k0, lda, tid);
    if constexpr (sizeof(TB) == 2)
      stage_f16<BNt>(Bs[buf], (const f16*)B + (size_t)n0 * ldb + k0, ldb, w, lane);
    else
      rb.load((const float*)B + (size_t)n0 * ldb + k0, ldb, tid);
  };
  auto stage_write = [&](int buf) {
    if constexpr (sizeof(TA) == 4) ra.write(As[buf], tid);
    if constexpr (sizeof(TB) == 4) rb.write(Bs[buf], tid);
  };
  auto compute = [&](int buf) {
    const int fr = lane & 15, q = lane >> 4;
#pragma unroll
    for (int kk = 0; kk < 2; kk++) {
      f16x8 af[MF], bf[NF];
#pragma unroll
      for (int i = 0; i < MF; i++) {
        const int r = wr * (BMt / 2) + i * 16 + fr;
        const int slot = (kk * 4 + q) ^ (r & 7);
        af[i] = *(const f16x8*)&As[buf][r][slot * 8];
      }
#pragma unroll
      for (int j = 0; j < NF; j++) {
        const int r = wc * (BNt / 2) + j * 16 + fr;
        const int slot = (kk * 4 + q) ^ (r & 7);
        bf[j] = *(const f16x8*)&Bs[buf][r][slot * 8];
      }
#pragma unroll
      for (int i = 0; i < MF; i++)
#pragma unroll
        for (int j = 0; j < NF; j++)
          acc[i][j] = __builtin_amdgcn_mfma_f32_16x16x32_f16(af[i], bf[j], acc[i][j], 0, 0, 0);
    }
  };

  // prologue
  stage_issue(0, 0);
  stage_write(0);
  __syncthreads();

  const int KT = K / BK;
  for (int kt = 0; kt < KT; kt++) {
    const int cur = kt & 1, nxt = cur ^ 1;
    if (kt + 1 < KT) stage_issue(nxt, (kt + 1) * BK);   // loads fly during compute
    compute(cur);
    if (kt + 1 < KT) stage_write(nxt);                  // f32 path: cvt + ds_write late
    __syncthreads();                                    // drains vmcnt+lgkm, flips buffers
  }

  // epilogue: D layout col = lane&15, row = (lane>>4)*4 + r
  const int fr = lane & 15;
  const int rg = (lane >> 4) << 2;
#pragma unroll
  for (int i = 0; i < MF; i++) {
#pragma unroll
    for (int j = 0; j < NF; j++) {
      const int col = n0 + wc * (BNt / 2) + j * 16 + fr;
      float bv = 0.f;
      if constexpr (BIAS) bv = bias[col];
#pragma unroll
      for (int r = 0; r < 4; r++) {
        const int row = m0 + wr * (BMt / 2) + i * 16 + rg + r;
        float v = acc[i][j][r] + bv;
        if constexpr (RELU) v = fmaxf(v, 0.f);
        C[(size_t)row * ldc + col] = (TC)v;
      }
    }
  }
}

// ---------------------------------------------------------------------------
// Transpose f32 -> fp16: in[R][Cn] f32 -> outT[Cn][R] fp16 (U only).
// ---------------------------------------------------------------------------
__global__ __launch_bounds__(256)
void transpose_f32_f16(const float* __restrict__ in, int R, int Cn,
                       f16* __restrict__ outT)
{
  __shared__ float t[32][33];
  const int r0 = blockIdx.x * 32;
  const int c0 = blockIdx.y * 32;
  const int c  = threadIdx.x & 31;
  const int rq = threadIdx.x >> 5;
#pragma unroll
  for (int i = 0; i < 4; i++)
    t[rq + i * 8][c] = in[(size_t)(r0 + rq + i * 8) * Cn + c0 + c];
  __syncthreads();
#pragma unroll
  for (int i = 0; i < 4; i++)
    outT[(size_t)(c0 + rq + i * 8) * R + r0 + c] = (f16)t[c][rq + i * 8];
}

// ---------------------------------------------------------------------------
// Row softmax over 2048 f32 scores; writes P fp16 packed into first 4KB of row.
// ---------------------------------------------------------------------------
__global__ __launch_bounds__(256)
void softmax_rows(float* __restrict__ S)
{
  float* row = S + (size_t)blockIdx.x * 2048;
  const int t = threadIdx.x;
  const float4 v0 = ((const float4*)row)[t];
  const float4 v1 = ((const float4*)row)[t + 256];

  float m = fmaxf(fmaxf(fmaxf(v0.x, v0.y), fmaxf(v0.z, v0.w)),
                  fmaxf(fmaxf(v1.x, v1.y), fmaxf(v1.z, v1.w)));
#pragma unroll
  for (int off = 32; off > 0; off >>= 1) m = fmaxf(m, __shfl_xor(m, off));
  __shared__ float red[8];
  if ((t & 63) == 0) red[t >> 6] = m;
  __syncthreads();
  m = fmaxf(fmaxf(red[0], red[1]), fmaxf(red[2], red[3]));

  float e0 = __expf(v0.x - m), e1 = __expf(v0.y - m), e2 = __expf(v0.z - m), e3 = __expf(v0.w - m);
  float e4 = __expf(v1.x - m), e5 = __expf(v1.y - m), e6 = __expf(v1.z - m), e7 = __expf(v1.w - m);
  float s = ((e0 + e1) + (e2 + e3)) + ((e4 + e5) + (e6 + e7));
#pragma unroll
  for (int off = 32; off > 0; off >>= 1) s += __shfl_xor(s, off);
  if ((t & 63) == 0) red[4 + (t >> 6)] = s;
  __syncthreads();
  const float inv = 1.f / (red[4] + red[5] + red[6] + red[7]);

  f16x4 o0, o1;
  o0[0] = (f16)(e0 * inv); o0[1] = (f16)(e1 * inv); o0[2] = (f16)(e2 * inv); o0[3] = (f16)(e3 * inv);
  o1[0] = (f16)(e4 * inv); o1[1] = (f16)(e5 * inv); o1[2] = (f16)(e6 * inv); o1[3] = (f16)(e7 * inv);
  f16x4* orow = (f16x4*)row;
  orow[t]       = o0;
  orow[t + 256] = o1;
}

// ---------------------------------------------------------------------------
extern "C" void kernel_launch(void* const* d_in, const int* in_sizes, int n_in,
                              void* d_out, int out_size, void* d_ws, size_t ws_size,
                              hipStream_t stream)
{
  const float* x1   = (const float*)d_in[0];
  const float* x2   = (const float*)d_in[1];
  const float* U    = (const float*)d_in[2];
  const float* bias = (const float*)d_in[3];
  const float* fcw  = (const float*)d_in[4];
  const float* fcb  = (const float*)d_in[5];
  float* out = (float*)d_out;

  const int S = 2048, D = 1024, E = 512, B = 8;
  const int SC = 1024;
  const size_t MB = 1ull << 20;

  // ws: UT 2MB | Y 4MB | W1T 2MB | Sb 8MB = 16MB (ws >= 19MB proven)
  char* w = (char*)d_ws;
  f16*   UT  = (f16*)(w);
  f16*   Y   = (f16*)(w + 2 * MB);
  f16*   W1T = (f16*)(w + 6 * MB);
  float* Sb  = (float*)(w + 8 * MB);

  transpose_f32_f16<<<dim3(32, 32), 256, 0, stream>>>(U, D, D, UT);

  for (int b = 0; b < B; b++) {
    const float* x1b = x1 + (size_t)b * S * D;
    const float* x2b = x2 + (size_t)b * S * D;

    // K1: Y = x2b @ U + bias (bias folded into Y columns)  grid 256
    gemm_tn<64, 128, float, f16, true, false, f16><<<dim3(S / 64, D / 128), 256, 0, stream>>>(
        x2b, D, UT, D, Y, D, bias, D);

    // W1T[e][t] = sum_d fcw[e,d] * x1b[t,d]   (= (x1 @ fcw^T)^T)  grid 128
    gemm_tn<64, 128, float, float, false, false, f16><<<dim3(E / 64, S / 128), 256, 0, stream>>>(
        fcw, D, x1b, D, W1T, S, nullptr, D);

    for (int s0 = 0; s0 < S; s0 += SC) {
      // K2: Sb = Y[s0:] @ x1b^T   grid 256
      gemm_tn<64, 128, f16, float, false, false, float><<<dim3(SC / 64, S / 128), 256, 0, stream>>>(
          Y + (size_t)s0 * D, D, x1b, D, Sb, S, nullptr, D);
      // K3: softmax -> P fp16 packed (lda 2S)
      softmax_rows<<<dim3(SC), 256, 0, stream>>>(Sb);
      // K4': out = relu(P @ W1T^T + fcb)   (K = t = 2048)  grid 128
      gemm_tn<64, 64, f16, f16, true, true, float><<<dim3(SC / 64, E / 64), 256, 0, stream>>>(
          (const f16*)Sb, 2 * S, W1T, S, out + ((size_t)b * S + s0) * E, E, fcb, S);
    }
  }
}

// Round 4
// 922.855 us; speedup vs baseline: 1.4950x; 1.3506x over previous
//
#include <hip/hip_runtime.h>
#include <hip/hip_fp16.h>
#include <cstddef>
#include <cstdint>

typedef _Float16 f16;
typedef _Float16 f16x8 __attribute__((ext_vector_type(8)));
typedef _Float16 f16x4 __attribute__((ext_vector_type(4)));
typedef float    f32x4 __attribute__((ext_vector_type(4)));

#define BK 64   // K-tile depth (fp16 elems); 2 MFMA k-steps per tile

// async 16B global->LDS (linear LDS dest = wave-uniform base + lane*16)
__device__ __forceinline__ void gload16(const void* g, void* lds) {
  __builtin_amdgcn_global_load_lds(
      (const __attribute__((address_space(1))) unsigned int*)g,
      (__attribute__((address_space(3))) unsigned int*)lds, 16, 0, 0);
}

// Stage an [R x 64] fp16 tile via global_load_lds. LDS row r holds global
// 8-elem slot s at slot s^(r&7) (rule-21 both-sides swizzle: source address
// pre-swizzled here, reader XORs identically).
template<int R>
__device__ __forceinline__ void stage_f16(f16 (*buf)[BK], const f16* __restrict__ src,
                                          int ld, int w, int lane) {
#pragma unroll
  for (int i = 0; i < R / 32; i++) {
    const int grp  = w * (R / 32) + i;          // wave-uniform
    const int r    = grp * 8 + (lane >> 3);
    const int slot = (lane & 7) ^ (r & 7);
    gload16(src + (size_t)r * ld + slot * 8, &buf[grp * 8][0]);
  }
}

// Reg-staging for f32 sources (T14 issue-early / write-late).
template<int R>
struct RegStage {
  static constexpr int NV = (R == 128) ? 8 : 4;   // float4 loads per thread
  float4 v[NV];
  __device__ __forceinline__ void load(const float* __restrict__ src, int ld, int tid) {
    const int r = (R == 128) ? (tid >> 1) : (tid >> 2);
    const int h = (R == 128) ? (tid & 1) * 32 : (tid & 3) * 16;
    const float* p = src + (size_t)r * ld + h;
#pragma unroll
    for (int j = 0; j < NV; j++) v[j] = ((const float4*)p)[j];
  }
  __device__ __forceinline__ void write(f16 (*buf)[BK], int tid) {
    const int r = (R == 128) ? (tid >> 1) : (tid >> 2);
    const int h = (R == 128) ? (tid & 1) * 32 : (tid & 3) * 16;
#pragma unroll
    for (int g = 0; g < NV / 2; g++) {
      const float4 a = v[g * 2], b = v[g * 2 + 1];
      f16x8 o;
      o[0] = (f16)a.x; o[1] = (f16)a.y; o[2] = (f16)a.z; o[3] = (f16)a.w;
      o[4] = (f16)b.x; o[5] = (f16)b.y; o[6] = (f16)b.z; o[7] = (f16)b.w;
      const int slot = (h / 8 + g) ^ (r & 7);
      *(f16x8*)&buf[r][slot * 8] = o;
    }
  }
};

// ---------------------------------------------------------------------------
// TN GEMM, double-buffered, grid.z-batched: per z, C = A@B^T (+bias)(+relu).
// fp16 operands: global_load_lds. f32 operands: reg-stage + cvt.
// Chunked XCD swizzle on (bx,by); requires gridDim.x*gridDim.y % 8 == 0.
// ---------------------------------------------------------------------------
template<int BMt, int BNt, typename TA, typename TB, bool BIAS, bool RELU, typename TC>
__global__ __launch_bounds__(256, 2)
void gemm_tn(const TA* __restrict__ A0, int lda, size_t sA,
             const TB* __restrict__ B0, int ldb, size_t sB,
             TC* __restrict__ C0, int ldc, size_t sC,
             const float* __restrict__ bias, int K)
{
  constexpr int MF = BMt / 32;
  constexpr int NF = BNt / 32;
  __shared__ f16 As[2][BMt][BK];
  __shared__ f16 Bs[2][BNt][BK];
  const int tid  = threadIdx.x;
  const int lane = tid & 63;
  const int w    = tid >> 6;
  const int wr   = w >> 1, wc = w & 1;

  // chunked bijective XCD swizzle (nxy % 8 == 0 for all our grids)
  const int gx = gridDim.x, nxy = gx * gridDim.y;
  int lin = blockIdx.y * gx + blockIdx.x;
  lin = (lin & 7) * (nxy >> 3) + (lin >> 3);
  const int m0 = (lin % gx) * BMt;
  const int n0 = (lin / gx) * BNt;

  const TA* A = A0 + (size_t)blockIdx.z * sA;
  const TB* B = B0 + (size_t)blockIdx.z * sB;
  TC*       C = C0 + (size_t)blockIdx.z * sC;

  f32x4 acc[MF][NF] = {};
  RegStage<BMt> ra;   // dead when TA == f16
  RegStage<BNt> rb;   // dead when TB == f16

  auto stage_issue = [&](int buf, int k0) {
    if constexpr (sizeof(TA) == 2)
      stage_f16<BMt>(As[buf], (const f16*)A + (size_t)m0 * lda + k0, lda, w, lane);
    else
      ra.load((const float*)A + (size_t)m0 * lda + k0, lda, tid);
    if constexpr (sizeof(TB) == 2)
      stage_f16<BNt>(Bs[buf], (const f16*)B + (size_t)n0 * ldb + k0, ldb, w, lane);
    else
      rb.load((const float*)B + (size_t)n0 * ldb + k0, ldb, tid);
  };
  auto stage_write = [&](int buf) {
    if constexpr (sizeof(TA) == 4) ra.write(As[buf], tid);
    if constexpr (sizeof(TB) == 4) rb.write(Bs[buf], tid);
  };
  auto compute = [&](int buf) {
    const int fr = lane & 15, q = lane >> 4;
#pragma unroll
    for (int kk = 0; kk < 2; kk++) {
      f16x8 af[MF], bf[NF];
#pragma unroll
      for (int i = 0; i < MF; i++) {
        const int r = wr * (BMt / 2) + i * 16 + fr;
        const int slot = (kk * 4 + q) ^ (r & 7);
        af[i] = *(const f16x8*)&As[buf][r][slot * 8];
      }
#pragma unroll
      for (int j = 0; j < NF; j++) {
        const int r = wc * (BNt / 2) + j * 16 + fr;
        const int slot = (kk * 4 + q) ^ (r & 7);
        bf[j] = *(const f16x8*)&Bs[buf][r][slot * 8];
      }
#pragma unroll
      for (int i = 0; i < MF; i++)
#pragma unroll
        for (int j = 0; j < NF; j++)
          acc[i][j] = __builtin_amdgcn_mfma_f32_16x16x32_f16(af[i], bf[j], acc[i][j], 0, 0, 0);
    }
  };

  stage_issue(0, 0);
  stage_write(0);
  __syncthreads();

  const int KT = K / BK;
  for (int kt = 0; kt < KT; kt++) {
    const int cur = kt & 1, nxt = cur ^ 1;
    if (kt + 1 < KT) stage_issue(nxt, (kt + 1) * BK);   // loads fly during compute
    compute(cur);
    if (kt + 1 < KT) stage_write(nxt);                  // f32 path: cvt + ds_write late
    __syncthreads();
  }

  // epilogue: D layout col = lane&15, row = (lane>>4)*4 + r
  const int fr = lane & 15;
  const int rg = (lane >> 4) << 2;
#pragma unroll
  for (int i = 0; i < MF; i++) {
#pragma unroll
    for (int j = 0; j < NF; j++) {
      const int col = n0 + wc * (BNt / 2) + j * 16 + fr;
      float bv = 0.f;
      if constexpr (BIAS) bv = bias[col];
#pragma unroll
      for (int r = 0; r < 4; r++) {
        const int row = m0 + wr * (BMt / 2) + i * 16 + rg + r;
        float v = acc[i][j][r] + bv;
        if constexpr (RELU) v = fmaxf(v, 0.f);
        C[(size_t)row * ldc + col] = (TC)v;
      }
    }
  }
}

// ---------------------------------------------------------------------------
__global__ __launch_bounds__(256)
void transpose_f32_f16(const float* __restrict__ in, int R, int Cn,
                       f16* __restrict__ outT)
{
  __shared__ float t[32][33];
  const int r0 = blockIdx.x * 32;
  const int c0 = blockIdx.y * 32;
  const int c  = threadIdx.x & 31;
  const int rq = threadIdx.x >> 5;
#pragma unroll
  for (int i = 0; i < 4; i++)
    t[rq + i * 8][c] = in[(size_t)(r0 + rq + i * 8) * Cn + c0 + c];
  __syncthreads();
#pragma unroll
  for (int i = 0; i < 4; i++)
    outT[(size_t)(c0 + rq + i * 8) * R + r0 + c] = (f16)t[c][rq + i * 8];
}

// f32 -> fp16 vector copy (8 elems/thread)
__global__ __launch_bounds__(256)
void copy_f32_f16(const float* __restrict__ in, f16* __restrict__ o)
{
  const size_t i = ((size_t)blockIdx.x * 256 + threadIdx.x) * 8;
  const float4 a = ((const float4*)(in + i))[0];
  const float4 b = ((const float4*)(in + i))[1];
  f16x8 v;
  v[0] = (f16)a.x; v[1] = (f16)a.y; v[2] = (f16)a.z; v[3] = (f16)a.w;
  v[4] = (f16)b.x; v[5] = (f16)b.y; v[6] = (f16)b.z; v[7] = (f16)b.w;
  *(f16x8*)(o + i) = v;
}

// ---------------------------------------------------------------------------
// Row softmax over 2048 f32 scores; writes P fp16 packed into first 4KB of row.
// ---------------------------------------------------------------------------
__global__ __launch_bounds__(256)
void softmax_rows(float* __restrict__ S)
{
  float* row = S + (size_t)blockIdx.x * 2048;
  const int t = threadIdx.x;
  const float4 v0 = ((const float4*)row)[t];
  const float4 v1 = ((const float4*)row)[t + 256];

  float m = fmaxf(fmaxf(fmaxf(v0.x, v0.y), fmaxf(v0.z, v0.w)),
                  fmaxf(fmaxf(v1.x, v1.y), fmaxf(v1.z, v1.w)));
#pragma unroll
  for (int off = 32; off > 0; off >>= 1) m = fmaxf(m, __shfl_xor(m, off));
  __shared__ float red[8];
  if ((t & 63) == 0) red[t >> 6] = m;
  __syncthreads();
  m = fmaxf(fmaxf(red[0], red[1]), fmaxf(red[2], red[3]));

  float e0 = __expf(v0.x - m), e1 = __expf(v0.y - m), e2 = __expf(v0.z - m), e3 = __expf(v0.w - m);
  float e4 = __expf(v1.x - m), e5 = __expf(v1.y - m), e6 = __expf(v1.z - m), e7 = __expf(v1.w - m);
  float s = ((e0 + e1) + (e2 + e3)) + ((e4 + e5) + (e6 + e7));
#pragma unroll
  for (int off = 32; off > 0; off >>= 1) s += __shfl_xor(s, off);
  if ((t & 63) == 0) red[4 + (t >> 6)] = s;
  __syncthreads();
  const float inv = 1.f / (red[4] + red[5] + red[6] + red[7]);

  f16x4 o0, o1;
  o0[0] = (f16)(e0 * inv); o0[1] = (f16)(e1 * inv); o0[2] = (f16)(e2 * inv); o0[3] = (f16)(e3 * inv);
  o1[0] = (f16)(e4 * inv); o1[1] = (f16)(e5 * inv); o1[2] = (f16)(e6 * inv); o1[3] = (f16)(e7 * inv);
  f16x4* orow = (f16x4*)row;
  orow[t]       = o0;
  orow[t + 256] = o1;
}

// ---------------------------------------------------------------------------
extern "C" void kernel_launch(void* const* d_in, const int* in_sizes, int n_in,
                              void* d_out, int out_size, void* d_ws, size_t ws_size,
                              hipStream_t stream)
{
  const float* x1   = (const float*)d_in[0];
  const float* x2   = (const float*)d_in[1];
  const float* U    = (const float*)d_in[2];
  const float* bias = (const float*)d_in[3];
  const float* fcw  = (const float*)d_in[4];
  const float* fcb  = (const float*)d_in[5];
  float* out = (float*)d_out;

  const int S = 2048, D = 1024, E = 512, B = 8;
  const int SC = 1024;
  const size_t MB = 1ull << 20;

  // ws: X1h 4MB | W1T 2MB | UT 2MB | Sb 8MB = 16MB (ws >= 19MB proven)
  char* w = (char*)d_ws;
  f16*   X1h = (f16*)(w);
  f16*   W1T = (f16*)(w + 4 * MB);
  f16*   UT  = (f16*)(w + 6 * MB);
  float* Sb  = (float*)(w + 8 * MB);

  // Y_all overlays d_out: Y[b] (f16, 2048x1024 = 2KB/row) aliases out[b]
  // (f32, 2048x512 = 2KB/row). K4' overwrites chunk rows only after K2 read them.
  f16* Yall = (f16*)d_out;

  // U -> UT fp16 (once)
  transpose_f32_f16<<<dim3(32, 32), 256, 0, stream>>>(U, D, D, UT);

  // K1 all batches: Y = x2@U + bias  (A=x2 f32, B=UT fp16), grid 1024, 2/CU
  gemm_tn<128, 128, float, f16, true, false, f16><<<dim3(S / 128, D / 128, B), 256, 0, stream>>>(
      x2, D, (size_t)S * D, UT, D, 0, Yall, D, (size_t)S * D, bias, D);

  for (int b = 0; b < B; b++) {
    const float* x1b = x1 + (size_t)b * S * D;
    f16* Yb = Yall + (size_t)b * S * D;

    // x1b -> X1h fp16 (grid 1024)
    copy_f32_f16<<<dim3(S * D / 2048), 256, 0, stream>>>(x1b, X1h);

    // W1T[e][t] = sum_d fcw[e,d]*x1b[t,d]  (A=fcw f32, B=X1h fp16), grid 128
    gemm_tn<64, 128, float, f16, false, false, f16><<<dim3(E / 64, S / 128), 256, 0, stream>>>(
        fcw, D, 0, X1h, D, 0, W1T, S, 0, nullptr, D);

    for (int s0 = 0; s0 < S; s0 += SC) {
      // K2: Sb = Y[s0:] @ X1h^T  (both fp16 gload_lds), grid 256
      gemm_tn<64, 128, f16, f16, false, false, float><<<dim3(SC / 64, S / 128), 256, 0, stream>>>(
          Yb + (size_t)s0 * D, D, 0, X1h, D, 0, Sb, S, 0, nullptr, D);
      // K3: softmax -> P fp16 packed (lda 2S)
      softmax_rows<<<dim3(SC), 256, 0, stream>>>(Sb);
      // K4': out rows [s0, s0+SC) = relu(P @ W1T^T + fcb), overwrites dead Y rows
      gemm_tn<64, 64, f16, f16, true, true, float><<<dim3(SC / 64, E / 64), 256, 0, stream>>>(
          (const f16*)Sb, 2 * S, 0, W1T, S, 0, out + ((size_t)b * S + s0) * E, E, 0, fcb, S);
    }
  }
}

// Round 5
// 739.955 us; speedup vs baseline: 1.8645x; 1.2472x over previous
//
#include <hip/hip_runtime.h>
#include <hip/hip_fp16.h>
#include <cstddef>
#include <cstdint>

typedef _Float16 f16;
typedef _Float16 f16x8 __attribute__((ext_vector_type(8)));
typedef _Float16 f16x4 __attribute__((ext_vector_type(4)));
typedef float    f32x4 __attribute__((ext_vector_type(4)));

#define BK 64   // K-tile depth (fp16 elems); 2 MFMA k-steps per tile

// async 16B global->LDS (linear LDS dest = wave-uniform base + lane*16)
__device__ __forceinline__ void gload16(const void* g, void* lds) {
  __builtin_amdgcn_global_load_lds(
      (const __attribute__((address_space(1))) unsigned int*)g,
      (__attribute__((address_space(3))) unsigned int*)lds, 16, 0, 0);
}

// Stage an [R x 64] fp16 tile via global_load_lds. LDS row r holds global
// 8-elem slot s at slot s^(r&7) (rule-21 both-sides swizzle: source address
// pre-swizzled here, reader XORs identically).
template<int R>
__device__ __forceinline__ void stage_f16(f16 (*buf)[BK], const f16* __restrict__ src,
                                          int ld, int w, int lane) {
#pragma unroll
  for (int i = 0; i < R / 32; i++) {
    const int grp  = w * (R / 32) + i;          // wave-uniform
    const int r    = grp * 8 + (lane >> 3);
    const int slot = (lane & 7) ^ (r & 7);
    gload16(src + (size_t)r * ld + slot * 8, &buf[grp * 8][0]);
  }
}

// Reg-staging for f32 sources (T14 issue-early / write-late).
template<int R>
struct RegStage {
  static constexpr int NV = (R == 128) ? 8 : 4;   // float4 loads per thread
  float4 v[NV];
  __device__ __forceinline__ void load(const float* __restrict__ src, int ld, int tid) {
    const int r = (R == 128) ? (tid >> 1) : (tid >> 2);
    const int h = (R == 128) ? (tid & 1) * 32 : (tid & 3) * 16;
    const float* p = src + (size_t)r * ld + h;
#pragma unroll
    for (int j = 0; j < NV; j++) v[j] = ((const float4*)p)[j];
  }
  __device__ __forceinline__ void write(f16 (*buf)[BK], int tid) {
    const int r = (R == 128) ? (tid >> 1) : (tid >> 2);
    const int h = (R == 128) ? (tid & 1) * 32 : (tid & 3) * 16;
#pragma unroll
    for (int g = 0; g < NV / 2; g++) {
      const float4 a = v[g * 2], b = v[g * 2 + 1];
      f16x8 o;
      o[0] = (f16)a.x; o[1] = (f16)a.y; o[2] = (f16)a.z; o[3] = (f16)a.w;
      o[4] = (f16)b.x; o[5] = (f16)b.y; o[6] = (f16)b.z; o[7] = (f16)b.w;
      const int slot = (h / 8 + g) ^ (r & 7);
      *(f16x8*)&buf[r][slot * 8] = o;
    }
  }
};

// ---------------------------------------------------------------------------
// TN GEMM, double-buffered: C[M][N] = A[M][K] @ B[N][K]^T (+bias[n]) (+relu).
// fp16 operands: global_load_lds. f32 operands: reg-stage + cvt.
// Chunked bijective XCD swizzle on (bx,by); requires nxy % 8 == 0.
// ---------------------------------------------------------------------------
template<int BMt, int BNt, typename TA, typename TB, bool BIAS, bool RELU, typename TC>
__global__ __launch_bounds__(256, 2)
void gemm_tn(const TA* __restrict__ A, int lda,
             const TB* __restrict__ B, int ldb,
             TC* __restrict__ C, int ldc,
             const float* __restrict__ bias, int K)
{
  constexpr int MF = BMt / 32;
  constexpr int NF = BNt / 32;
  __shared__ f16 As[2][BMt][BK];
  __shared__ f16 Bs[2][BNt][BK];
  const int tid  = threadIdx.x;
  const int lane = tid & 63;
  const int w    = tid >> 6;
  const int wr   = w >> 1, wc = w & 1;

  const int gx = gridDim.x, nxy = gx * gridDim.y;
  int lin = blockIdx.y * gx + blockIdx.x;
  lin = (lin & 7) * (nxy >> 3) + (lin >> 3);
  const int m0 = (lin % gx) * BMt;
  const int n0 = (lin / gx) * BNt;

  f32x4 acc[MF][NF] = {};
  RegStage<BMt> ra;   // dead when TA == f16
  RegStage<BNt> rb;   // dead when TB == f16

  auto stage_issue = [&](int buf, int k0) {
    if constexpr (sizeof(TA) == 2)
      stage_f16<BMt>(As[buf], (const f16*)A + (size_t)m0 * lda + k0, lda, w, lane);
    else
      ra.load((const float*)A + (size_t)m0 * lda + k0, lda, tid);
    if constexpr (sizeof(TB) == 2)
      stage_f16<BNt>(Bs[buf], (const f16*)B + (size_t)n0 * ldb + k0, ldb, w, lane);
    else
      rb.load((const float*)B + (size_t)n0 * ldb + k0, ldb, tid);
  };
  auto stage_write = [&](int buf) {
    if constexpr (sizeof(TA) == 4) ra.write(As[buf], tid);
    if constexpr (sizeof(TB) == 4) rb.write(Bs[buf], tid);
  };
  auto compute = [&](int buf) {
    const int fr = lane & 15, q = lane >> 4;
#pragma unroll
    for (int kk = 0; kk < 2; kk++) {
      f16x8 af[MF], bf[NF];
#pragma unroll
      for (int i = 0; i < MF; i++) {
        const int r = wr * (BMt / 2) + i * 16 + fr;
        const int slot = (kk * 4 + q) ^ (r & 7);
        af[i] = *(const f16x8*)&As[buf][r][slot * 8];
      }
#pragma unroll
      for (int j = 0; j < NF; j++) {
        const int r = wc * (BNt / 2) + j * 16 + fr;
        const int slot = (kk * 4 + q) ^ (r & 7);
        bf[j] = *(const f16x8*)&Bs[buf][r][slot * 8];
      }
#pragma unroll
      for (int i = 0; i < MF; i++)
#pragma unroll
        for (int j = 0; j < NF; j++)
          acc[i][j] = __builtin_amdgcn_mfma_f32_16x16x32_f16(af[i], bf[j], acc[i][j], 0, 0, 0);
    }
  };

  stage_issue(0, 0);
  stage_write(0);
  __syncthreads();

  const int KT = K / BK;
  for (int kt = 0; kt < KT; kt++) {
    const int cur = kt & 1, nxt = cur ^ 1;
    if (kt + 1 < KT) stage_issue(nxt, (kt + 1) * BK);   // loads fly during compute
    compute(cur);
    if (kt + 1 < KT) stage_write(nxt);                  // f32 path: cvt + ds_write late
    __syncthreads();
  }

  // epilogue: D layout col = lane&15, row = (lane>>4)*4 + r
  const int fr = lane & 15;
  const int rg = (lane >> 4) << 2;
#pragma unroll
  for (int i = 0; i < MF; i++) {
#pragma unroll
    for (int j = 0; j < NF; j++) {
      const int col = n0 + wc * (BNt / 2) + j * 16 + fr;
      float bv = 0.f;
      if constexpr (BIAS) bv = bias[col];
#pragma unroll
      for (int r = 0; r < 4; r++) {
        const int row = m0 + wr * (BMt / 2) + i * 16 + rg + r;
        float v = acc[i][j][r] + bv;
        if constexpr (RELU) v = fmaxf(v, 0.f);
        C[(size_t)row * ldc + col] = (TC)v;
      }
    }
  }
}

// f32 -> fp16 vector copy (8 elems/thread)
__global__ __launch_bounds__(256)
void copy_f32_f16(const float* __restrict__ in, f16* __restrict__ o)
{
  const size_t i = ((size_t)blockIdx.x * 256 + threadIdx.x) * 8;
  const float4 a = ((const float4*)(in + i))[0];
  const float4 b = ((const float4*)(in + i))[1];
  f16x8 v;
  v[0] = (f16)a.x; v[1] = (f16)a.y; v[2] = (f16)a.z; v[3] = (f16)a.w;
  v[4] = (f16)b.x; v[5] = (f16)b.y; v[6] = (f16)b.z; v[7] = (f16)b.w;
  *(f16x8*)(o + i) = v;
}

// bT[row] = dot(x1[row, :1024], bias)  (exact f32; 1 row per wave, 4 rows/block)
__global__ __launch_bounds__(256)
void bias_dot(const float* __restrict__ x1, const float* __restrict__ bias,
              float* __restrict__ bT)
{
  const int row  = blockIdx.x * 4 + (threadIdx.x >> 6);
  const int lane = threadIdx.x & 63;
  const float4* r = (const float4*)(x1 + (size_t)row * 1024);
  const float4* bb = (const float4*)bias;
  float acc = 0.f;
#pragma unroll
  for (int j = 0; j < 4; j++) {
    const float4 a = r[lane + j * 64];
    const float4 b = bb[lane + j * 64];
    acc += a.x * b.x + a.y * b.y + a.z * b.z + a.w * b.w;
  }
#pragma unroll
  for (int off = 32; off > 0; off >>= 1) acc += __shfl_xor(acc, off);
  if (lane == 0) bT[row] = acc;
}

// ---------------------------------------------------------------------------
// Row softmax over 2048 f32 scores; writes P fp16 packed into first 4KB of row.
// ---------------------------------------------------------------------------
__global__ __launch_bounds__(256)
void softmax_rows(float* __restrict__ S)
{
  float* row = S + (size_t)blockIdx.x * 2048;
  const int t = threadIdx.x;
  const float4 v0 = ((const float4*)row)[t];
  const float4 v1 = ((const float4*)row)[t + 256];

  float m = fmaxf(fmaxf(fmaxf(v0.x, v0.y), fmaxf(v0.z, v0.w)),
                  fmaxf(fmaxf(v1.x, v1.y), fmaxf(v1.z, v1.w)));
#pragma unroll
  for (int off = 32; off > 0; off >>= 1) m = fmaxf(m, __shfl_xor(m, off));
  __shared__ float red[8];
  if ((t & 63) == 0) red[t >> 6] = m;
  __syncthreads();
  m = fmaxf(fmaxf(red[0], red[1]), fmaxf(red[2], red[3]));

  float e0 = __expf(v0.x - m), e1 = __expf(v0.y - m), e2 = __expf(v0.z - m), e3 = __expf(v0.w - m);
  float e4 = __expf(v1.x - m), e5 = __expf(v1.y - m), e6 = __expf(v1.z - m), e7 = __expf(v1.w - m);
  float s = ((e0 + e1) + (e2 + e3)) + ((e4 + e5) + (e6 + e7));
#pragma unroll
  for (int off = 32; off > 0; off >>= 1) s += __shfl_xor(s, off);
  if ((t & 63) == 0) red[4 + (t >> 6)] = s;
  __syncthreads();
  const float inv = 1.f / (red[4] + red[5] + red[6] + red[7]);

  f16x4 o0, o1;
  o0[0] = (f16)(e0 * inv); o0[1] = (f16)(e1 * inv); o0[2] = (f16)(e2 * inv); o0[3] = (f16)(e3 * inv);
  o1[0] = (f16)(e4 * inv); o1[1] = (f16)(e5 * inv); o1[2] = (f16)(e6 * inv); o1[3] = (f16)(e7 * inv);
  f16x4* orow = (f16x4*)row;
  orow[t]       = o0;
  orow[t + 256] = o1;
}

// ---------------------------------------------------------------------------
extern "C" void kernel_launch(void* const* d_in, const int* in_sizes, int n_in,
                              void* d_out, int out_size, void* d_ws, size_t ws_size,
                              hipStream_t stream)
{
  const float* x1   = (const float*)d_in[0];
  const float* x2   = (const float*)d_in[1];
  const float* U    = (const float*)d_in[2];
  const float* bias = (const float*)d_in[3];
  const float* fcw  = (const float*)d_in[4];
  const float* fcb  = (const float*)d_in[5];
  float* out = (float*)d_out;

  const int S = 2048, D = 1024, E = 512, B = 8;
  const size_t MB = 1ull << 20;

  // ws: W2 4MB | W1T 2MB | bT 64KB | Sb (16MB if it fits, else 8MB)
  char* w = (char*)d_ws;
  f16*   W2  = (f16*)(w);
  f16*   W1T = (f16*)(w + 4 * MB);
  float* bT  = (float*)(w + 6 * MB);
  float* Sb  = (float*)(w + 6 * MB + 256 * 1024);

  const size_t sb_off = 6 * MB + 256 * 1024;
  const int SC = (ws_size >= sb_off + (size_t)S * 2048 * 4) ? 2048 : 1024;

  // X2h_all overlays d_out exactly (8*2048*1024 f16 == 8*2048*512 f32).
  // K4' overwrites batch-b rows only AFTER K2 consumed them (stream-ordered).
  f16* X2h = (f16*)d_out;

  // 1. x2 (all batches) -> fp16, one pass
  copy_f32_f16<<<dim3(B * S * D / 2048), 256, 0, stream>>>(x2, X2h);
  // 2. bT_all[b*S+t] = x1[b,t,:]. bias, one pass
  bias_dot<<<dim3(B * S / 4), 256, 0, stream>>>(x1, bias, bT);

  for (int b = 0; b < B; b++) {
    const float* x1b = x1 + (size_t)b * S * D;
    const f16*   X2b = X2h + (size_t)b * S * D;

    // K0: W2[t][d] = sum_e x1b[t,e] U[d,e]   (A=x1b f32, B=U f32)  grid 256
    gemm_tn<64, 128, float, float, false, false, f16><<<dim3(S / 64, D / 128), 256, 0, stream>>>(
        x1b, D, U, D, W2, D, nullptr, D);

    // W1T[e][t] = sum_d fcw[e,d] x1b[t,d]    (A=fcw f32, B=x1b f32) grid 256
    gemm_tn<64, 64, float, float, false, false, f16><<<dim3(E / 64, S / 64), 256, 0, stream>>>(
        fcw, D, x1b, D, W1T, S, nullptr, D);

    for (int s0 = 0; s0 < S; s0 += SC) {
      // K2: Sb[s][t] = sum_d X2b[s0+s,d] W2[t,d] + bT[t]  (fp16 x fp16)
      gemm_tn<64, 128, f16, f16, true, false, float><<<dim3(SC / 64, S / 128), 256, 0, stream>>>(
          X2b + (size_t)s0 * D, D, W2, D, Sb, S, bT + (size_t)b * S, D);
      // K3: softmax -> P fp16 packed (lda 2S)
      softmax_rows<<<dim3(SC), 256, 0, stream>>>(Sb);
      // K4': out rows [s0, s0+SC) = relu(P @ W1T^T + fcb)   (K = t = 2048)
      gemm_tn<64, 64, f16, f16, true, true, float><<<dim3(SC / 64, E / 64), 256, 0, stream>>>(
          (const f16*)Sb, 2 * S, W1T, S, out + ((size_t)b * S + s0) * E, E, fcb, S);
    }
  }
}